// Round 4
// baseline (111.470 us; speedup 1.0000x reference)
//
#include <hip/hip_runtime.h>
#include <hip/hip_bf16.h>
#include <math.h>

#define B_ROWS 4096
#define NTOT   8192
#define DDIM   256
#define CSCALE 1.6986436f      // sqrt(2*log2(e)); zn scaled so A.B = 2*log2(e)*cos
#define NPART  8

typedef __attribute__((ext_vector_type(8)))  short short8;   // 8 bf16
typedef __attribute__((ext_vector_type(16))) float f32x16;

static __device__ inline unsigned short f2bf(float x) {
    union { float f; unsigned u; } v; v.f = x;
    unsigned r = v.u + 0x7fffu + ((v.u >> 16) & 1u);  // RNE
    return (unsigned short)(r >> 16);
}

// ---- kernel 1: fused normalize (scaled bf16) + positive-pair sims + partials zeroing ----
__global__ __launch_bounds__(256) void norm_kernel(
        const float* __restrict__ zi, const float* __restrict__ zj,
        unsigned short* __restrict__ zn, float* __restrict__ simpos,
        float* __restrict__ parts) {
    int pair = blockIdx.x * 4 + (threadIdx.x >> 6);
    int lane = threadIdx.x & 63;
    float4 vi = reinterpret_cast<const float4*>(zi + (size_t)pair * DDIM)[lane];
    float4 vj = reinterpret_cast<const float4*>(zj + (size_t)pair * DDIM)[lane];
    float ssi = vi.x*vi.x + vi.y*vi.y + vi.z*vi.z + vi.w*vi.w;
    float ssj = vj.x*vj.x + vj.y*vj.y + vj.z*vj.z + vj.w*vj.w;
    float dij = vi.x*vj.x + vi.y*vj.y + vi.z*vj.z + vi.w*vj.w;
    #pragma unroll
    for (int o = 32; o > 0; o >>= 1) {
        ssi += __shfl_xor(ssi, o);
        ssj += __shfl_xor(ssj, o);
        dij += __shfl_xor(dij, o);
    }
    float invi = 1.0f / fmaxf(sqrtf(ssi), 1e-8f);
    float invj = 1.0f / fmaxf(sqrtf(ssj), 1e-8f);
    float si = CSCALE * invi, sj = CSCALE * invj;
    ushort4 hi4, hj4;
    hi4.x = f2bf(vi.x * si); hi4.y = f2bf(vi.y * si);
    hi4.z = f2bf(vi.z * si); hi4.w = f2bf(vi.w * si);
    hj4.x = f2bf(vj.x * sj); hj4.y = f2bf(vj.y * sj);
    hj4.z = f2bf(vj.z * sj); hj4.w = f2bf(vj.w * sj);
    *reinterpret_cast<ushort4*>(zn + (size_t)pair * DDIM + lane * 4) = hi4;
    *reinterpret_cast<ushort4*>(zn + (size_t)(pair + B_ROWS) * DDIM + lane * 4) = hj4;
    if (lane == 0) simpos[pair] = 2.0f * dij * invi * invj;   // logits = cos/tau
    if (blockIdx.x < 256) parts[blockIdx.x * 256 + threadIdx.x] = 0.0f;
}

// ---- kernel 2: triangular fused sim + exp2 + row/col exp-sums ----
// 4160 uniform units (128 rows x 64 cols, upper triangle, strict): strip ti
// (128 rows) has 128-2*ti units; C(ti) = ti*(129-ti). 1040 blocks x 4 units.
// 4 waves x 32 resident A-rows, 32x32x16 MFMA (B read once per wave per unit).
__global__ __launch_bounds__(256, 3) void sim_kernel(
        const unsigned short* __restrict__ zn, float* __restrict__ parts) {
    __shared__ __align__(16) unsigned char tile[64 * 512];   // 32 KB
    __shared__ float csum_lds[4][256];                       // 4 KB
    __shared__ int   c0s[4];

    int tid  = threadIdx.x;
    int wid  = tid >> 6;
    int lane = tid & 63;
    int l31  = lane & 31;
    int hi   = lane >> 5;
    float* part = parts + (size_t)(blockIdx.x & (NPART - 1)) * NTOT;

    int u0 = blockIdx.x * 4;
    int ti = (int)((129.0f - sqrtf(16641.0f - 4.0f * (float)u0)) * 0.5f);
    if (ti > 63) ti = 63;
    if (ti < 0)  ti = 0;
    while (ti > 0 && u0 < ti * (129 - ti)) --ti;
    while (u0 >= (ti + 1) * (128 - ti)) ++ti;

    short8 a[16];
    int rowBase = 0;

    // A fragments for 32x32x16: lane holds row=l31, k-half hi (8 bf16 per step)
    auto loadA = [&](int strip) {
        rowBase = strip * 128 + wid * 32;
        const unsigned short* ap = zn + (size_t)(rowBase + l31) * DDIM + hi * 8;
        #pragma unroll
        for (int k = 0; k < 16; ++k)
            a[k] = *reinterpret_cast<const short8*>(ap + k * 16);
    };
    loadA(ti);

    float rsum[16];
    #pragma unroll
    for (int r = 0; r < 16; ++r) rsum[r] = 0.0f;

    auto flushRows = [&]() {
        #pragma unroll
        for (int r = 0; r < 16; ++r) {
            float s = rsum[r];
            #pragma unroll
            for (int m = 16; m >= 1; m >>= 1) s += __shfl_xor(s, m);
            if (l31 == 0)
                atomicAdd(&part[rowBase + (r & 3) + 8 * (r >> 2) + 4 * hi], s);
            rsum[r] = 0.0f;
        }
    };

    #pragma unroll 1
    for (int ui = 0; ui < 4; ++ui) {
        int u = u0 + ui;
        while (u >= (ti + 1) * (128 - ti)) {   // crossed into next strip
            flushRows();
            ++ti;
            loadA(ti);
        }
        int colchunk = u - ti * (129 - ti);
        int c0 = ti * 128 + colchunk * 64;
        if (tid == 0) c0s[ui] = c0;

        __syncthreads();   // protect tile before overwrite
        // stage 64 cols x 256 K bf16 = 32 KB, full 5-bit XOR swizzle
        #pragma unroll
        for (int p = 0; p < 8; ++p) {
            int id = p * 256 + tid;
            int tr = id >> 5, ck = id & 31;
            uint4 v = *reinterpret_cast<const uint4*>(
                zn + (size_t)(c0 + tr) * DDIM + ck * 8);
            *reinterpret_cast<uint4*>(tile + tr * 512 + ((ck ^ (tr & 31)) << 4)) = v;
        }
        __syncthreads();

        bool crossing = (colchunk < 2);   // unit straddles/precedes the diagonal
        const unsigned char* bb = tile + (size_t)l31 * 512;

        #pragma unroll
        for (int ct = 0; ct < 2; ++ct) {
            const unsigned char* bbase = bb + ct * (32 * 512);
            f32x16 acc = {0.f,0.f,0.f,0.f,0.f,0.f,0.f,0.f,
                          0.f,0.f,0.f,0.f,0.f,0.f,0.f,0.f};
            #pragma unroll
            for (int k = 0; k < 16; ++k) {
                short8 b = *reinterpret_cast<const short8*>(
                    bbase + ((((2 * k + hi) ^ l31)) << 4));
                acc = __builtin_amdgcn_mfma_f32_32x32x16_bf16(a[k], b, acc, 0, 0, 0);
            }
            int gcol = c0 + ct * 32 + l31;
            int growBase = rowBase + 4 * hi;
            float cs = 0.0f;
            #pragma unroll
            for (int r = 0; r < 16; ++r) {
                float e = exp2f(acc[r]);          // zn pre-scaled: acc = 2*log2e*cos
                if (crossing) {
                    int grow = growBase + (r & 3) + 8 * (r >> 2);
                    e = (gcol > grow) ? e : 0.0f; // strict upper triangle
                }
                rsum[r] += e;
                cs += e;
            }
            cs += __shfl_xor(cs, 32);
            if (hi == 0) csum_lds[wid][ui * 64 + ct * 32 + l31] = cs;
        }
    }
    flushRows();

    // ---- flush cols: sum 4 waves' slices, one atomic per col ----
    __syncthreads();
    {
        int ui = tid >> 6, col = tid & 63;
        int idx = ui * 64 + col;
        float s = csum_lds[0][idx] + csum_lds[1][idx]
                + csum_lds[2][idx] + csum_lds[3][idx];
        atomicAdd(&part[c0s[ui] + col], s);
    }
}

// ---- kernel 3: loss partials; out zeroed by memset, atomicAdd final ----
__global__ __launch_bounds__(256) void finalize_kernel(
        const float* __restrict__ parts, const float* __restrict__ simpos,
        float* __restrict__ out) {
    __shared__ float red[4];
    int r = blockIdx.x * 512 + threadIdx.x;
    float acc = 0.0f;
    #pragma unroll
    for (int rr = 0; rr < 2; ++rr, r += 256) {
        float s = 0.0f;
        #pragma unroll
        for (int p = 0; p < NPART; ++p) s += parts[p * NTOT + r];
        acc += logf(s) - simpos[r & (B_ROWS - 1)];
    }
    #pragma unroll
    for (int o = 32; o > 0; o >>= 1) acc += __shfl_xor(acc, o);
    if ((threadIdx.x & 63) == 0) red[threadIdx.x >> 6] = acc;
    __syncthreads();
    if (threadIdx.x == 0)
        atomicAdd(out, (red[0] + red[1] + red[2] + red[3]) / (float)NTOT);
}

extern "C" void kernel_launch(void* const* d_in, const int* in_sizes, int n_in,
                              void* d_out, int out_size, void* d_ws, size_t ws_size,
                              hipStream_t stream) {
    const float* zi = (const float*)d_in[0];
    const float* zj = (const float*)d_in[1];
    float* out = (float*)d_out;

    unsigned short* zn = (unsigned short*)d_ws;                        // 4 MB
    float* parts  = (float*)((char*)d_ws + (size_t)NTOT * DDIM * 2);   // 256 KB
    float* simpos = parts + NPART * NTOT;                              // 32 KB

    hipMemsetAsync(out, 0, sizeof(float), stream);
    norm_kernel<<<B_ROWS / 4, 256, 0, stream>>>(zi, zj, zn, simpos, parts);
    sim_kernel<<<1040, 256, 0, stream>>>(zn, parts);
    finalize_kernel<<<16, 256, 0, stream>>>(parts, simpos, out);
}

// Round 5
// 102.495 us; speedup vs baseline: 1.0876x; 1.0876x over previous
//
#include <hip/hip_runtime.h>
#include <hip/hip_bf16.h>
#include <math.h>

#define B_ROWS 4096
#define NTOT   8192
#define DDIM   256
#define CSCALE 1.6986436f      // sqrt(2*log2(e)); zn scaled so A.B = 2*log2(e)*cos
#define NPART  8

typedef __attribute__((ext_vector_type(8)))  short short8;   // 8 bf16
typedef __attribute__((ext_vector_type(16))) float f32x16;

static __device__ inline unsigned short f2bf(float x) {
    union { float f; unsigned u; } v; v.f = x;
    unsigned r = v.u + 0x7fffu + ((v.u >> 16) & 1u);  // RNE
    return (unsigned short)(r >> 16);
}

// ---- kernel 1: fused normalize (scaled bf16) + positive-pair sims + partials zeroing ----
__global__ __launch_bounds__(256) void norm_kernel(
        const float* __restrict__ zi, const float* __restrict__ zj,
        unsigned short* __restrict__ zn, float* __restrict__ simpos,
        float* __restrict__ parts) {
    int pair = blockIdx.x * 4 + (threadIdx.x >> 6);
    int lane = threadIdx.x & 63;
    float4 vi = reinterpret_cast<const float4*>(zi + (size_t)pair * DDIM)[lane];
    float4 vj = reinterpret_cast<const float4*>(zj + (size_t)pair * DDIM)[lane];
    float ssi = vi.x*vi.x + vi.y*vi.y + vi.z*vi.z + vi.w*vi.w;
    float ssj = vj.x*vj.x + vj.y*vj.y + vj.z*vj.z + vj.w*vj.w;
    float dij = vi.x*vj.x + vi.y*vj.y + vi.z*vj.z + vi.w*vj.w;
    #pragma unroll
    for (int o = 32; o > 0; o >>= 1) {
        ssi += __shfl_xor(ssi, o);
        ssj += __shfl_xor(ssj, o);
        dij += __shfl_xor(dij, o);
    }
    float invi = 1.0f / fmaxf(sqrtf(ssi), 1e-8f);
    float invj = 1.0f / fmaxf(sqrtf(ssj), 1e-8f);
    float si = CSCALE * invi, sj = CSCALE * invj;
    ushort4 hi4, hj4;
    hi4.x = f2bf(vi.x * si); hi4.y = f2bf(vi.y * si);
    hi4.z = f2bf(vi.z * si); hi4.w = f2bf(vi.w * si);
    hj4.x = f2bf(vj.x * sj); hj4.y = f2bf(vj.y * sj);
    hj4.z = f2bf(vj.z * sj); hj4.w = f2bf(vj.w * sj);
    *reinterpret_cast<ushort4*>(zn + (size_t)pair * DDIM + lane * 4) = hi4;
    *reinterpret_cast<ushort4*>(zn + (size_t)(pair + B_ROWS) * DDIM + lane * 4) = hj4;
    if (lane == 0) simpos[pair] = 2.0f * dij * invi * invj;   // logits = cos/tau
    if (blockIdx.x < 256) parts[blockIdx.x * 256 + threadIdx.x] = 0.0f;
}

// ---- kernel 2 body: one block = 256 rows x 128 cols (2 x 64-col units), static ----
// 4 waves x 64 rows (a[2][16] resident, all indices compile-time constants).
template<bool CROSS>
static __device__ __forceinline__ void sim_body(
        const unsigned short* __restrict__ zn, float* __restrict__ part,
        unsigned char* __restrict__ tile, float (* __restrict__ csum_lds)[128],
        int waveRow, int c0base) {
    int tid  = threadIdx.x;
    int wid  = tid >> 6;
    int lane = tid & 63;
    int l31  = lane & 31;
    int hi   = lane >> 5;

    // A fragments: 64 rows per wave, two 32-row sets. 128 VGPRs, static.
    short8 a[2][16];
    #pragma unroll
    for (int rs = 0; rs < 2; ++rs) {
        const unsigned short* ap = zn + (size_t)(waveRow + 32 * rs + l31) * DDIM + hi * 8;
        #pragma unroll
        for (int k = 0; k < 16; ++k)
            a[rs][k] = *reinterpret_cast<const short8*>(ap + k * 16);
    }

    float rsum[2][16];
    #pragma unroll
    for (int rs = 0; rs < 2; ++rs)
        #pragma unroll
        for (int r = 0; r < 16; ++r) rsum[rs][r] = 0.0f;

    #pragma unroll
    for (int ui = 0; ui < 2; ++ui) {
        int c0 = c0base + ui * 64;
        __syncthreads();   // protect tile before overwrite
        // stage 64 cols x 256 K bf16 = 32 KB, full 5-bit XOR swizzle (0 conflicts)
        #pragma unroll
        for (int p = 0; p < 8; ++p) {
            int id = p * 256 + tid;
            int tr = id >> 5, ck = id & 31;
            uint4 v = *reinterpret_cast<const uint4*>(
                zn + (size_t)(c0 + tr) * DDIM + ck * 8);
            *reinterpret_cast<uint4*>(tile + tr * 512 + ((ck ^ (tr & 31)) << 4)) = v;
        }
        __syncthreads();

        #pragma unroll
        for (int ct = 0; ct < 2; ++ct) {
            const unsigned char* bbase = tile + (size_t)(ct * 32 + l31) * 512;
            f32x16 acc[2];
            #pragma unroll
            for (int rs = 0; rs < 2; ++rs)
                #pragma unroll
                for (int r = 0; r < 16; ++r) acc[rs][r] = 0.0f;

            #pragma unroll
            for (int k = 0; k < 16; ++k) {   // one b-frag feeds both row-sets
                short8 bf = *reinterpret_cast<const short8*>(
                    bbase + (((2 * k + hi) ^ l31) << 4));
                acc[0] = __builtin_amdgcn_mfma_f32_32x32x16_bf16(a[0][k], bf, acc[0], 0, 0, 0);
                acc[1] = __builtin_amdgcn_mfma_f32_32x32x16_bf16(a[1][k], bf, acc[1], 0, 0, 0);
            }

            int gcol = c0 + ct * 32 + l31;
            float cs = 0.0f;
            #pragma unroll
            for (int rs = 0; rs < 2; ++rs) {
                int growBase = waveRow + 32 * rs + 4 * hi;
                #pragma unroll
                for (int r = 0; r < 16; ++r) {
                    float e = exp2f(acc[rs][r]);       // zn pre-scaled: acc = 2*log2e*cos
                    if (CROSS) {
                        int grow = growBase + (r & 3) + 8 * (r >> 2);
                        e = (gcol > grow) ? e : 0.0f;  // strict upper triangle
                    }
                    rsum[rs][r] += e;
                    cs += e;
                }
            }
            cs += __shfl_xor(cs, 32);
            if (hi == 0) csum_lds[wid][ui * 64 + ct * 32 + l31] = cs;
        }
    }

    // ---- flush rows: reduce across 32 col-lanes, one atomic per row ----
    #pragma unroll
    for (int rs = 0; rs < 2; ++rs)
        #pragma unroll
        for (int r = 0; r < 16; ++r) {
            float s = rsum[rs][r];
            #pragma unroll
            for (int m = 16; m >= 1; m >>= 1) s += __shfl_xor(s, m);
            if (l31 == 0)
                atomicAdd(&part[waveRow + 32 * rs + 4 * hi + (r & 3) + 8 * (r >> 2)], s);
        }

    // ---- flush cols: sum 4 waves' slices, one atomic per col ----
    __syncthreads();
    if (tid < 128) {
        float s = csum_lds[0][tid] + csum_lds[1][tid]
                + csum_lds[2][tid] + csum_lds[3][tid];
        atomicAdd(&part[c0base + tid], s);
    }
}

// 1056 blocks: strip s (32 strips of 256 rows) has 64-2s blocks of 128 cols,
// prefix(s) = s*(65-s). Blocks never cross strips -> fully static register use.
__global__ __launch_bounds__(256, 2) void sim_kernel(
        const unsigned short* __restrict__ zn, float* __restrict__ parts) {
    __shared__ __align__(16) unsigned char tile[64 * 512];   // 32 KB
    __shared__ float csum_lds[4][128];                       // 2 KB

    int b = blockIdx.x;
    int s = (int)((65.0f - sqrtf(4225.0f - 4.0f * (float)b)) * 0.5f);
    if (s < 0) s = 0;
    if (s > 31) s = 31;
    while (s > 0 && b < s * (65 - s)) --s;
    while (b >= (s + 1) * (64 - s)) ++s;
    int rel = b - s * (65 - s);

    int waveRow = s * 256 + (threadIdx.x >> 6) * 64;
    int c0base  = s * 256 + rel * 128;
    float* part = parts + (size_t)(b & (NPART - 1)) * NTOT;

    if (rel < 2) sim_body<true >(zn, part, tile, csum_lds, waveRow, c0base);
    else         sim_body<false>(zn, part, tile, csum_lds, waveRow, c0base);
}

// ---- kernel 3: loss partials; out zeroed by memset, atomicAdd final ----
__global__ __launch_bounds__(256) void finalize_kernel(
        const float* __restrict__ parts, const float* __restrict__ simpos,
        float* __restrict__ out) {
    __shared__ float red[4];
    int r = blockIdx.x * 512 + threadIdx.x;
    float acc = 0.0f;
    #pragma unroll
    for (int rr = 0; rr < 2; ++rr, r += 256) {
        float s = 0.0f;
        #pragma unroll
        for (int p = 0; p < NPART; ++p) s += parts[p * NTOT + r];
        acc += logf(s) - simpos[r & (B_ROWS - 1)];
    }
    #pragma unroll
    for (int o = 32; o > 0; o >>= 1) acc += __shfl_xor(acc, o);
    if ((threadIdx.x & 63) == 0) red[threadIdx.x >> 6] = acc;
    __syncthreads();
    if (threadIdx.x == 0)
        atomicAdd(out, (red[0] + red[1] + red[2] + red[3]) / (float)NTOT);
}

extern "C" void kernel_launch(void* const* d_in, const int* in_sizes, int n_in,
                              void* d_out, int out_size, void* d_ws, size_t ws_size,
                              hipStream_t stream) {
    const float* zi = (const float*)d_in[0];
    const float* zj = (const float*)d_in[1];
    float* out = (float*)d_out;

    unsigned short* zn = (unsigned short*)d_ws;                        // 4 MB
    float* parts  = (float*)((char*)d_ws + (size_t)NTOT * DDIM * 2);   // 256 KB
    float* simpos = parts + NPART * NTOT;                              // 16 KB

    hipMemsetAsync(out, 0, sizeof(float), stream);
    norm_kernel<<<B_ROWS / 4, 256, 0, stream>>>(zi, zj, zn, simpos, parts);
    sim_kernel<<<1056, 256, 0, stream>>>(zn, parts);
    finalize_kernel<<<16, 256, 0, stream>>>(parts, simpos, out);
}

// Round 6
// 74.061 us; speedup vs baseline: 1.5051x; 1.3839x over previous
//
#include <hip/hip_runtime.h>
#include <hip/hip_bf16.h>
#include <math.h>

#define B_ROWS 4096
#define NTOT   8192
#define DDIM   256
#define CSCALE 1.6986436f      // sqrt(2*log2(e)); zn scaled so A.B = 2*log2(e)*cos
#define NPART  8

typedef __attribute__((ext_vector_type(8)))  short short8;   // 8 bf16
typedef __attribute__((ext_vector_type(16))) float f32x16;

static __device__ inline unsigned short f2bf(float x) {
    union { float f; unsigned u; } v; v.f = x;
    unsigned r = v.u + 0x7fffu + ((v.u >> 16) & 1u);  // RNE
    return (unsigned short)(r >> 16);
}

// ---- kernel 1: fused normalize (scaled bf16) + positive-pair sims + partials zeroing ----
__global__ __launch_bounds__(256) void norm_kernel(
        const float* __restrict__ zi, const float* __restrict__ zj,
        unsigned short* __restrict__ zn, float* __restrict__ simpos,
        float* __restrict__ parts) {
    int pair = blockIdx.x * 4 + (threadIdx.x >> 6);
    int lane = threadIdx.x & 63;
    float4 vi = reinterpret_cast<const float4*>(zi + (size_t)pair * DDIM)[lane];
    float4 vj = reinterpret_cast<const float4*>(zj + (size_t)pair * DDIM)[lane];
    float ssi = vi.x*vi.x + vi.y*vi.y + vi.z*vi.z + vi.w*vi.w;
    float ssj = vj.x*vj.x + vj.y*vj.y + vj.z*vj.z + vj.w*vj.w;
    float dij = vi.x*vj.x + vi.y*vj.y + vi.z*vj.z + vi.w*vj.w;
    #pragma unroll
    for (int o = 32; o > 0; o >>= 1) {
        ssi += __shfl_xor(ssi, o);
        ssj += __shfl_xor(ssj, o);
        dij += __shfl_xor(dij, o);
    }
    float invi = 1.0f / fmaxf(sqrtf(ssi), 1e-8f);
    float invj = 1.0f / fmaxf(sqrtf(ssj), 1e-8f);
    float si = CSCALE * invi, sj = CSCALE * invj;
    ushort4 hi4, hj4;
    hi4.x = f2bf(vi.x * si); hi4.y = f2bf(vi.y * si);
    hi4.z = f2bf(vi.z * si); hi4.w = f2bf(vi.w * si);
    hj4.x = f2bf(vj.x * sj); hj4.y = f2bf(vj.y * sj);
    hj4.z = f2bf(vj.z * sj); hj4.w = f2bf(vj.w * sj);
    *reinterpret_cast<ushort4*>(zn + (size_t)pair * DDIM + lane * 4) = hi4;
    *reinterpret_cast<ushort4*>(zn + (size_t)(pair + B_ROWS) * DDIM + lane * 4) = hj4;
    if (lane == 0) simpos[pair] = 2.0f * dij * invi * invj;   // logits = cos/tau
    if (blockIdx.x < 256) parts[blockIdx.x * 256 + threadIdx.x] = 0.0f;  // zero 64K floats
}

// ---- kernel 2 body: one block = 128 rows x 128 cols (2 x 64-col units), static ----
// 4 waves x 32 resident A-rows (a[16] = 64 VGPR, all indices compile-time).
// 32x32x16 MFMA: B-frag LDS traffic = 1/32 B/FLOP (LDS-pipe balanced).
template<bool CROSS>
static __device__ __forceinline__ void sim_body(
        const unsigned short* __restrict__ zn, float* __restrict__ part,
        unsigned char* __restrict__ tile, float (* __restrict__ csum_lds)[128],
        int waveRow, int c0base) {
    int tid  = threadIdx.x;
    int wid  = tid >> 6;
    int lane = tid & 63;
    int l31  = lane & 31;
    int hi   = lane >> 5;

    // A fragments: 32 rows per wave resident. 64 VGPRs, fully static.
    short8 a[16];
    {
        const unsigned short* ap = zn + (size_t)(waveRow + l31) * DDIM + hi * 8;
        #pragma unroll
        for (int k = 0; k < 16; ++k)
            a[k] = *reinterpret_cast<const short8*>(ap + k * 16);
    }

    float rsum[16];
    #pragma unroll
    for (int r = 0; r < 16; ++r) rsum[r] = 0.0f;

    #pragma unroll
    for (int ui = 0; ui < 2; ++ui) {
        int c0 = c0base + ui * 64;
        __syncthreads();   // protect tile before overwrite
        // stage 64 cols x 256 K bf16 = 32 KB, full 5-bit XOR swizzle (0 conflicts);
        // two passes of 4 loads to cap in-flight register pressure.
        #pragma unroll
        for (int g = 0; g < 2; ++g) {
            uint4 t[4];
            #pragma unroll
            for (int p = 0; p < 4; ++p) {
                int id = (g * 4 + p) * 256 + tid;
                int tr = id >> 5, ck = id & 31;
                t[p] = *reinterpret_cast<const uint4*>(
                    zn + (size_t)(c0 + tr) * DDIM + ck * 8);
            }
            #pragma unroll
            for (int p = 0; p < 4; ++p) {
                int id = (g * 4 + p) * 256 + tid;
                int tr = id >> 5, ck = id & 31;
                *reinterpret_cast<uint4*>(tile + tr * 512 + ((ck ^ (tr & 31)) << 4)) = t[p];
            }
        }
        __syncthreads();

        #pragma unroll
        for (int ct = 0; ct < 2; ++ct) {
            const unsigned char* bbase = tile + (size_t)(ct * 32 + l31) * 512;
            f32x16 acc;
            #pragma unroll
            for (int r = 0; r < 16; ++r) acc[r] = 0.0f;
            #pragma unroll
            for (int k = 0; k < 16; ++k) {
                short8 bf = *reinterpret_cast<const short8*>(
                    bbase + (((2 * k + hi) ^ l31) << 4));
                acc = __builtin_amdgcn_mfma_f32_32x32x16_bf16(a[k], bf, acc, 0, 0, 0);
            }
            int gcol = c0 + ct * 32 + l31;
            int growBase = waveRow + 4 * hi;
            float cs = 0.0f;
            #pragma unroll
            for (int r = 0; r < 16; ++r) {
                float e = exp2f(acc[r]);           // zn pre-scaled: acc = 2*log2e*cos
                if (CROSS) {
                    int grow = growBase + (r & 3) + 8 * (r >> 2);
                    e = (gcol > grow) ? e : 0.0f;  // strict upper triangle
                }
                rsum[r] += e;
                cs += e;
            }
            cs += __shfl_xor(cs, 32);              // merge hi-halves (same col set)
            if (hi == 0) csum_lds[wid][ui * 64 + ct * 32 + l31] = cs;
        }
    }

    // ---- flush rows: reduce across 32 col-lanes, one atomic per row ----
    #pragma unroll
    for (int r = 0; r < 16; ++r) {
        float s = rsum[r];
        #pragma unroll
        for (int m = 16; m >= 1; m >>= 1) s += __shfl_xor(s, m);
        if (l31 == 0)
            atomicAdd(&part[waveRow + 4 * hi + (r & 3) + 8 * (r >> 2)], s);
    }

    // ---- flush cols: sum 4 waves' slices, one atomic per col ----
    __syncthreads();
    if (tid < 128) {
        float s = csum_lds[0][tid] + csum_lds[1][tid]
                + csum_lds[2][tid] + csum_lds[3][tid];
        atomicAdd(&part[c0base + tid], s);
    }
}

// 2080 uniform blocks: strip s (64 strips of 128 rows) has 64-s blocks of 128
// cols starting at the diagonal; prefix(s) = 64s - s(s-1)/2. rel==0 => CROSS.
__global__ __launch_bounds__(256, 3) void sim_kernel(
        const unsigned short* __restrict__ zn, float* __restrict__ parts) {
    __shared__ __align__(16) unsigned char tile[64 * 512];   // 32 KB
    __shared__ float csum_lds[4][128];                       // 2 KB

    int b = blockIdx.x;
    int s = (int)(64.5f - sqrtf(4160.25f - 2.0f * (float)b));
    if (s < 0) s = 0;
    if (s > 63) s = 63;
    while (s > 0 && b < 64 * s - (s * (s - 1)) / 2) --s;
    while (b >= 64 * (s + 1) - ((s + 1) * s) / 2) ++s;
    int rel = b - (64 * s - (s * (s - 1)) / 2);

    int waveRow = s * 128 + (threadIdx.x >> 6) * 32;
    int c0base  = (s + rel) * 128;
    float* part = parts + (size_t)(b & (NPART - 1)) * NTOT;

    if (rel == 0) sim_body<true >(zn, part, tile, csum_lds, waveRow, c0base);
    else          sim_body<false>(zn, part, tile, csum_lds, waveRow, c0base);
}

// ---- kernel 3: loss = sum_r (log(sum_p parts[p][r]) - simpos[r % B]) / N ----
__global__ __launch_bounds__(1024) void finalize_kernel(
        const float* __restrict__ parts, const float* __restrict__ simpos,
        float* __restrict__ out) {
    __shared__ float red[16];
    int tid = threadIdx.x;
    float acc = 0.0f;
    #pragma unroll
    for (int rr = 0; rr < 8; ++rr) {
        int r = rr * 1024 + tid;
        float s = 0.0f;
        #pragma unroll
        for (int p = 0; p < NPART; ++p) s += parts[p * NTOT + r];
        acc += logf(s) - simpos[r & (B_ROWS - 1)];
    }
    #pragma unroll
    for (int o = 32; o > 0; o >>= 1) acc += __shfl_xor(acc, o);
    if ((tid & 63) == 0) red[tid >> 6] = acc;
    __syncthreads();
    if (tid == 0) {
        float t = 0.0f;
        #pragma unroll
        for (int w = 0; w < 16; ++w) t += red[w];
        out[0] = t / (float)NTOT;
    }
}

extern "C" void kernel_launch(void* const* d_in, const int* in_sizes, int n_in,
                              void* d_out, int out_size, void* d_ws, size_t ws_size,
                              hipStream_t stream) {
    const float* zi = (const float*)d_in[0];
    const float* zj = (const float*)d_in[1];
    float* out = (float*)d_out;

    unsigned short* zn = (unsigned short*)d_ws;                        // 4 MB
    float* parts  = (float*)((char*)d_ws + (size_t)NTOT * DDIM * 2);   // 256 KB
    float* simpos = parts + NPART * NTOT;                              // 16 KB

    norm_kernel<<<B_ROWS / 4, 256, 0, stream>>>(zi, zj, zn, simpos, parts);
    sim_kernel<<<2080, 256, 0, stream>>>(zn, parts);
    finalize_kernel<<<1, 1024, 0, stream>>>(parts, simpos, out);
}